// Round 2
// baseline (846.191 us; speedup 1.0000x reference)
//
#include <hip/hip_runtime.h>
#include <hip/hip_bf16.h>
#include <stdint.h>

typedef float    f32x4 __attribute__((ext_vector_type(4)));
typedef __bf16   bf16x8 __attribute__((ext_vector_type(8)));
typedef uint16_t u16;
typedef uint16_t u16x8 __attribute__((ext_vector_type(8)));
typedef uint16_t u16x4 __attribute__((ext_vector_type(4)));

__device__ __forceinline__ u16 f2bf(float f) {
  uint32_t u = __builtin_bit_cast(uint32_t, f);
  u += 0x7fffu + ((u >> 16) & 1u);
  return (u16)(u >> 16);
}

__device__ __forceinline__ f32x4 mfma16(u16x8 a, u16x8 b, f32x4 c) {
  return __builtin_amdgcn_mfma_f32_16x16x32_bf16(
      __builtin_bit_cast(bf16x8, a), __builtin_bit_cast(bf16x8, b), c, 0, 0, 0);
}

// ---------------- prep kernels ----------------
__global__ void conv_kernel(const float* __restrict__ src, u16* __restrict__ dst, int n4) {
  int i = blockIdx.x * blockDim.x + threadIdx.x;
  if (i >= n4) return;
  f32x4 v = *(const f32x4*)(src + (size_t)i * 4);
  u16x4 o;
  #pragma unroll
  for (int j = 0; j < 4; ++j) o[j] = f2bf(v[j]);
  *(u16x4*)(dst + (size_t)i * 4) = o;
}

__global__ void maskpack_kernel(const int* __restrict__ mask,
                                unsigned long long* __restrict__ bits) {
  int t = blockIdx.x * 256 + threadIdx.x;
  int mv = __builtin_nontemporal_load(mask + t);
  unsigned long long bal = __ballot(mv != 0);
  if ((threadIdx.x & 63) == 0) bits[t >> 6] = bal;
}

// ---------------- projection GEMM: P = X @ Wq^T + bq ----------------
// grid (8 colblk, 32 rowblk, 3 src). 256 thr = 4 waves, wave -> 64x64 out.
__global__ __launch_bounds__(256) void proj_kernel(
    const float* __restrict__ qin, const float* __restrict__ kin,
    const float* __restrict__ vin, const u16* __restrict__ wb,
    const float* __restrict__ bias,
    u16* __restrict__ qp, u16* __restrict__ kp, u16* __restrict__ vpt) {
  __shared__ __attribute__((aligned(16))) u16 lds_a[128][72];
  __shared__ __attribute__((aligned(16))) u16 lds_b[128][72];
  const int tid = threadIdx.x;
  const int lane = tid & 63, wv = tid >> 6;
  const int wr = wv >> 1, wc = wv & 1;
  const int g = lane >> 4, li = lane & 15;
  const int nb = blockIdx.x, mb = blockIdx.y, src = blockIdx.z;
  const float* A = (src == 0) ? qin : (src == 1) ? kin : vin;

  const int arow = tid >> 1;
  const int acol = (tid & 1) * 32;

  f32x4 acc[4][4];
  #pragma unroll
  for (int m = 0; m < 4; ++m)
    #pragma unroll
    for (int n = 0; n < 4; ++n) acc[m][n] = f32x4{0.f, 0.f, 0.f, 0.f};

  const float* aptr = A + (size_t)(mb * 128 + arow) * 1024 + acol;
  const u16*   bptr = wb + (size_t)(nb * 128 + arow) * 1024 + acol;

  for (int kt = 0; kt < 16; ++kt) {
    f32x4 af[8];
    #pragma unroll
    for (int i = 0; i < 8; ++i) af[i] = *(const f32x4*)(aptr + kt * 64 + i * 4);
    #pragma unroll
    for (int i = 0; i < 4; ++i) {
      u16x8 p;
      #pragma unroll
      for (int j = 0; j < 8; ++j) p[j] = f2bf(af[i * 2 + (j >> 2)][j & 3]);
      *(u16x8*)&lds_a[arow][acol + i * 8] = p;
    }
    #pragma unroll
    for (int i = 0; i < 4; ++i)
      *(u16x8*)&lds_b[arow][acol + i * 8] = *(const u16x8*)(bptr + kt * 64 + i * 8);
    __syncthreads();
    #pragma unroll
    for (int kk = 0; kk < 2; ++kk) {
      const int kof = kk * 32 + g * 8;
      u16x8 afr[4], bfr[4];
      #pragma unroll
      for (int m = 0; m < 4; ++m) afr[m] = *(const u16x8*)&lds_a[wr * 64 + m * 16 + li][kof];
      #pragma unroll
      for (int n = 0; n < 4; ++n) bfr[n] = *(const u16x8*)&lds_b[wc * 64 + n * 16 + li][kof];
      #pragma unroll
      for (int m = 0; m < 4; ++m)
        #pragma unroll
        for (int n = 0; n < 4; ++n) acc[m][n] = mfma16(afr[m], bfr[n], acc[m][n]);
    }
    __syncthreads();
  }

  #pragma unroll
  for (int n = 0; n < 4; ++n) {
    const int col = nb * 128 + wc * 64 + n * 16 + li;
    const float bv = bias[col];
    const int h = col >> 6, hd = col & 63;
    #pragma unroll
    for (int m = 0; m < 4; ++m) {
      const int row0 = mb * 128 + wr * 64 + m * 16 + g * 4;
      const int bb = row0 >> 11, s0 = row0 & 2047;
      if (src < 2) {
        u16* dst = (src == 0) ? qp : kp;
        #pragma unroll
        for (int r = 0; r < 4; ++r)
          dst[(((size_t)bb * 16 + h) * 2048 + s0 + r) * 64 + hd] = f2bf(acc[m][n][r] + bv);
      } else {
        u16x4 p;
        #pragma unroll
        for (int r = 0; r < 4; ++r) p[r] = f2bf(acc[m][n][r] + bv);
        *(u16x4*)&vpt[(((size_t)bb * 16 + h) * 64 + hd) * 2048 + s0] = p;
      }
    }
  }
}

// ---------------- fused attention ----------------
// grid (32 qtile, 16 h, 2 b), 256 thr = 4 waves; wave owns 16 q-rows.
__global__ __launch_bounds__(256) void attn_kernel(
    const u16* __restrict__ qp, const u16* __restrict__ kp,
    const u16* __restrict__ vpt, const unsigned long long* __restrict__ mbits,
    float* __restrict__ attnw, u16* __restrict__ ctx) {
  __shared__ __attribute__((aligned(16))) u16 q_lds[64][72];
  __shared__ __attribute__((aligned(16))) u16 k_lds[64][72];
  __shared__ __attribute__((aligned(16))) u16 v_lds[64][72];
  __shared__ __attribute__((aligned(16))) u16 w_lds[64][72];
  __shared__ unsigned long long m_lds[64][32];

  const int tid = threadIdx.x;
  const int lane = tid & 63, wv = tid >> 6;
  const int g = lane >> 4, li = lane & 15;
  const int qt = blockIdx.x, h = blockIdx.y, b = blockIdx.z;
  const int bh = b * 16 + h;
  const int q0 = qt * 64;
  const float scale = 0.125f;

  const int srow = tid >> 2;
  const int scol = (tid & 3) * 16;

  {
    const u16* qsrc = qp + ((size_t)bh * 2048 + q0 + srow) * 64 + scol;
    *(u16x8*)&q_lds[srow][scol] = *(const u16x8*)qsrc;
    *(u16x8*)&q_lds[srow][scol + 8] = *(const u16x8*)(qsrc + 8);
    const int mw0 = (tid & 3) * 8;
    #pragma unroll
    for (int i = 0; i < 8; ++i)
      m_lds[srow][mw0 + i] = mbits[((size_t)b * 2048 + q0 + srow) * 32 + mw0 + i];
  }
  __syncthreads();

  float mrun[4], lrun[4];
  #pragma unroll
  for (int r = 0; r < 4; ++r) { mrun[r] = -1e30f; lrun[r] = 0.f; }

  // ---- pass 1: stats ----
  for (int kt = 0; kt < 32; ++kt) {
    const u16* ksrc = kp + ((size_t)bh * 2048 + kt * 64 + srow) * 64 + scol;
    *(u16x8*)&k_lds[srow][scol] = *(const u16x8*)ksrc;
    *(u16x8*)&k_lds[srow][scol + 8] = *(const u16x8*)(ksrc + 8);
    __syncthreads();
    f32x4 sc[4];
    #pragma unroll
    for (int n = 0; n < 4; ++n) sc[n] = f32x4{0.f, 0.f, 0.f, 0.f};
    #pragma unroll
    for (int kk = 0; kk < 2; ++kk) {
      const int kof = kk * 32 + g * 8;
      u16x8 aq = *(const u16x8*)&q_lds[wv * 16 + li][kof];
      #pragma unroll
      for (int n = 0; n < 4; ++n)
        sc[n] = mfma16(aq, *(const u16x8*)&k_lds[n * 16 + li][kof], sc[n]);
    }
    #pragma unroll
    for (int r = 0; r < 4; ++r) {
      const unsigned long long mw = m_lds[wv * 16 + g * 4 + r][kt];
      float pm = -1e30f;
      #pragma unroll
      for (int n = 0; n < 4; ++n) {
        float sv = ((mw >> (n * 16 + li)) & 1ull) ? sc[n][r] * scale : -1e9f;
        sc[n][r] = sv;
        pm = fmaxf(pm, sv);
      }
      #pragma unroll
      for (int off = 1; off < 16; off <<= 1) pm = fmaxf(pm, __shfl_xor(pm, off, 16));
      const float mnew = fmaxf(mrun[r], pm);
      float ps = 0.f;
      #pragma unroll
      for (int n = 0; n < 4; ++n) ps += __expf(sc[n][r] - mnew);
      #pragma unroll
      for (int off = 1; off < 16; off <<= 1) ps += __shfl_xor(ps, off, 16);
      lrun[r] = lrun[r] * __expf(mrun[r] - mnew) + ps;
      mrun[r] = mnew;
    }
    __syncthreads();
  }

  float inv[4];
  #pragma unroll
  for (int r = 0; r < 4; ++r) inv[r] = 1.f / lrun[r];

  f32x4 cacc[4];
  #pragma unroll
  for (int n = 0; n < 4; ++n) cacc[n] = f32x4{0.f, 0.f, 0.f, 0.f};

  // ---- pass 2: weights out + PV ----
  for (int kt = 0; kt < 32; ++kt) {
    const u16* ksrc = kp + ((size_t)bh * 2048 + kt * 64 + srow) * 64 + scol;
    *(u16x8*)&k_lds[srow][scol] = *(const u16x8*)ksrc;
    *(u16x8*)&k_lds[srow][scol + 8] = *(const u16x8*)(ksrc + 8);
    const u16* vsrc = vpt + ((size_t)bh * 64 + srow) * 2048 + kt * 64 + scol;
    *(u16x8*)&v_lds[srow][scol] = *(const u16x8*)vsrc;
    *(u16x8*)&v_lds[srow][scol + 8] = *(const u16x8*)(vsrc + 8);
    __syncthreads();
    f32x4 sc[4];
    #pragma unroll
    for (int n = 0; n < 4; ++n) sc[n] = f32x4{0.f, 0.f, 0.f, 0.f};
    #pragma unroll
    for (int kk = 0; kk < 2; ++kk) {
      const int kof = kk * 32 + g * 8;
      u16x8 aq = *(const u16x8*)&q_lds[wv * 16 + li][kof];
      #pragma unroll
      for (int n = 0; n < 4; ++n)
        sc[n] = mfma16(aq, *(const u16x8*)&k_lds[n * 16 + li][kof], sc[n]);
    }
    #pragma unroll
    for (int r = 0; r < 4; ++r) {
      const int row_l = wv * 16 + g * 4 + r;
      const unsigned long long mw = m_lds[row_l][kt];
      float* wdst = attnw + ((size_t)bh * 2048 + q0 + row_l) * 2048 + kt * 64;
      #pragma unroll
      for (int n = 0; n < 4; ++n) {
        float sv = ((mw >> (n * 16 + li)) & 1ull) ? sc[n][r] * scale : -1e9f;
        float wn = __expf(sv - mrun[r]) * inv[r];
        __builtin_nontemporal_store(wn, wdst + n * 16 + li);
        w_lds[row_l][n * 16 + li] = f2bf(wn);
      }
    }
    __syncthreads();
    #pragma unroll
    for (int kk = 0; kk < 2; ++kk) {
      const int kof = kk * 32 + g * 8;
      u16x8 aw = *(const u16x8*)&w_lds[wv * 16 + li][kof];
      #pragma unroll
      for (int n = 0; n < 4; ++n)
        cacc[n] = mfma16(aw, *(const u16x8*)&v_lds[n * 16 + li][kof], cacc[n]);
    }
    __syncthreads();
  }

  #pragma unroll
  for (int n = 0; n < 4; ++n)
    #pragma unroll
    for (int r = 0; r < 4; ++r) {
      const int row_l = wv * 16 + g * 4 + r;
      ctx[((size_t)b * 2048 + q0 + row_l) * 1024 + h * 64 + n * 16 + li] = f2bf(cacc[n][r]);
    }
}

// ---------------- output GEMM: out = ctx @ Wout^T + bout ----------------
__global__ __launch_bounds__(256) void out_kernel(
    const u16* __restrict__ ctxp, const u16* __restrict__ wb,
    const float* __restrict__ bias, float* __restrict__ out) {
  __shared__ __attribute__((aligned(16))) u16 lds_a[128][72];
  __shared__ __attribute__((aligned(16))) u16 lds_b[128][72];
  const int tid = threadIdx.x;
  const int lane = tid & 63, wv = tid >> 6;
  const int wr = wv >> 1, wc = wv & 1;
  const int g = lane >> 4, li = lane & 15;
  const int nb = blockIdx.x, mb = blockIdx.y;

  const int arow = tid >> 1;
  const int acol = (tid & 1) * 32;

  f32x4 acc[4][4];
  #pragma unroll
  for (int m = 0; m < 4; ++m)
    #pragma unroll
    for (int n = 0; n < 4; ++n) acc[m][n] = f32x4{0.f, 0.f, 0.f, 0.f};

  const u16* aptr = ctxp + (size_t)(mb * 128 + arow) * 1024 + acol;
  const u16* bptr = wb + (size_t)(nb * 128 + arow) * 1024 + acol;

  for (int kt = 0; kt < 16; ++kt) {
    #pragma unroll
    for (int i = 0; i < 4; ++i) {
      *(u16x8*)&lds_a[arow][acol + i * 8] = *(const u16x8*)(aptr + kt * 64 + i * 8);
      *(u16x8*)&lds_b[arow][acol + i * 8] = *(const u16x8*)(bptr + kt * 64 + i * 8);
    }
    __syncthreads();
    #pragma unroll
    for (int kk = 0; kk < 2; ++kk) {
      const int kof = kk * 32 + g * 8;
      u16x8 afr[4], bfr[4];
      #pragma unroll
      for (int m = 0; m < 4; ++m) afr[m] = *(const u16x8*)&lds_a[wr * 64 + m * 16 + li][kof];
      #pragma unroll
      for (int n = 0; n < 4; ++n) bfr[n] = *(const u16x8*)&lds_b[wc * 64 + n * 16 + li][kof];
      #pragma unroll
      for (int m = 0; m < 4; ++m)
        #pragma unroll
        for (int n = 0; n < 4; ++n) acc[m][n] = mfma16(afr[m], bfr[n], acc[m][n]);
    }
    __syncthreads();
  }

  #pragma unroll
  for (int n = 0; n < 4; ++n) {
    const int col = nb * 128 + wc * 64 + n * 16 + li;
    const float bv = bias[col];
    #pragma unroll
    for (int m = 0; m < 4; ++m) {
      const int row0 = mb * 128 + wr * 64 + m * 16 + g * 4;
      #pragma unroll
      for (int r = 0; r < 4; ++r)
        __builtin_nontemporal_store(acc[m][n][r] + bv, out + (size_t)(row0 + r) * 1024 + col);
    }
  }
}

extern "C" void kernel_launch(void* const* d_in, const int* in_sizes, int n_in,
                              void* d_out, int out_size, void* d_ws, size_t ws_size,
                              hipStream_t stream) {
  const float* q    = (const float*)d_in[0];
  const float* k    = (const float*)d_in[1];
  const float* v    = (const float*)d_in[2];
  const int*   mask = (const int*)d_in[3];
  const float* Wq   = (const float*)d_in[4];
  const float* bq   = (const float*)d_in[5];
  const float* Wout = (const float*)d_in[6];
  const float* bout = (const float*)d_in[7];
  float* out   = (float*)d_out;
  float* attnw = out + (size_t)2 * 2048 * 1024;

  u16* wq_bf   = (u16*)d_ws;
  u16* wout_bf = wq_bf + (1 << 20);
  u16* qp      = wout_bf + (1 << 20);
  u16* kp      = qp + (4 << 20);
  u16* vpt     = kp + (4 << 20);
  u16* ctx     = vpt + (4 << 20);
  unsigned long long* mbits = (unsigned long long*)(ctx + (4 << 20));

  conv_kernel<<<1024, 256, 0, stream>>>(Wq, wq_bf, 262144);
  conv_kernel<<<1024, 256, 0, stream>>>(Wout, wout_bf, 262144);
  maskpack_kernel<<<32768, 256, 0, stream>>>(mask, mbits);
  proj_kernel<<<dim3(8, 32, 3), 256, 0, stream>>>(q, k, v, wq_bf, bq, qp, kp, vpt);
  attn_kernel<<<dim3(32, 16, 2), 256, 0, stream>>>(qp, kp, vpt, mbits, attnw, ctx);
  out_kernel<<<dim3(8, 32), 256, 0, stream>>>(ctx, wout_bf, bout, out);
}

// Round 3
// 784.763 us; speedup vs baseline: 1.0783x; 1.0783x over previous
//
#include <hip/hip_runtime.h>
#include <hip/hip_bf16.h>
#include <stdint.h>

typedef float    f32x4 __attribute__((ext_vector_type(4)));
typedef __bf16   bf16x8 __attribute__((ext_vector_type(8)));
typedef uint16_t u16;
typedef uint16_t u16x8 __attribute__((ext_vector_type(8)));
typedef uint16_t u16x4 __attribute__((ext_vector_type(4)));
typedef unsigned long long u64;

__device__ __forceinline__ u16 f2bf(float f) {
  uint32_t u = __builtin_bit_cast(uint32_t, f);
  u += 0x7fffu + ((u >> 16) & 1u);
  return (u16)(u >> 16);
}

__device__ __forceinline__ f32x4 mfma16(u16x8 a, u16x8 b, f32x4 c) {
  return __builtin_amdgcn_mfma_f32_16x16x32_bf16(
      __builtin_bit_cast(bf16x8, a), __builtin_bit_cast(bf16x8, b), c, 0, 0, 0);
}

// ---------------- prep kernels ----------------
__global__ void conv_kernel(const float* __restrict__ src, u16* __restrict__ dst, int n4) {
  int i = blockIdx.x * blockDim.x + threadIdx.x;
  if (i >= n4) return;
  f32x4 v = *(const f32x4*)(src + (size_t)i * 4);
  u16x4 o;
  #pragma unroll
  for (int j = 0; j < 4; ++j) o[j] = f2bf(v[j]);
  *(u16x4*)(dst + (size_t)i * 4) = o;
}

// q,k,v fp32 -> bf16 concat into xb[12288][1024]
__global__ void convqkv_kernel(const float* __restrict__ q, const float* __restrict__ k,
                               const float* __restrict__ v, u16* __restrict__ xb) {
  int t = blockIdx.x * 256 + threadIdx.x;   // 1,572,864 threads, 8 elems each
  int src = t >> 19;
  size_t off = (size_t)(t & 524287) * 8;
  const float* p = ((src == 0) ? q : (src == 1) ? k : v) + off;
  f32x4 a = *(const f32x4*)p;
  f32x4 b = *(const f32x4*)(p + 4);
  u16x8 o;
  #pragma unroll
  for (int j = 0; j < 4; ++j) { o[j] = f2bf(a[j]); o[4 + j] = f2bf(b[j]); }
  *(u16x8*)(xb + (size_t)t * 8) = o;
}

__global__ void maskpack_kernel(const int* __restrict__ mask,
                                u64* __restrict__ bits) {
  int t = blockIdx.x * 256 + threadIdx.x;
  int mv = __builtin_nontemporal_load(mask + t);
  u64 bal = __ballot(mv != 0);
  if ((threadIdx.x & 63) == 0) bits[t >> 6] = bal;
}

// ---------------- projection GEMM: P = [q;k;v] @ Wq^T + bq ----------------
// grid (8 colblk, 96 rowblk). 256 thr = 4 waves, wave -> 64x64 out.
__global__ __launch_bounds__(256) void proj_kernel(
    const u16* __restrict__ xb, const u16* __restrict__ wb,
    const float* __restrict__ bias,
    u16* __restrict__ qp, u16* __restrict__ kp, u16* __restrict__ vpt) {
  __shared__ __attribute__((aligned(16))) u16 lds_a[128][72];
  __shared__ __attribute__((aligned(16))) u16 lds_b[128][72];
  const int tid = threadIdx.x;
  const int lane = tid & 63, wv = tid >> 6;
  const int wr = wv >> 1, wc = wv & 1;
  const int g = lane >> 4, li = lane & 15;
  const int nb = blockIdx.x, mb = blockIdx.y;
  const int arow = tid >> 1;
  const int acol = (tid & 1) * 32;

  f32x4 acc[4][4];
  #pragma unroll
  for (int m = 0; m < 4; ++m)
    #pragma unroll
    for (int n = 0; n < 4; ++n) acc[m][n] = f32x4{0.f, 0.f, 0.f, 0.f};

  const u16* aptr = xb + (size_t)(mb * 128 + arow) * 1024 + acol;
  const u16* bptr = wb + (size_t)(nb * 128 + arow) * 1024 + acol;

  u16x8 ar[4], br[4];
  #pragma unroll
  for (int i = 0; i < 4; ++i) {
    ar[i] = *(const u16x8*)(aptr + i * 8);
    br[i] = *(const u16x8*)(bptr + i * 8);
  }

  for (int kt = 0; kt < 16; ++kt) {
    #pragma unroll
    for (int i = 0; i < 4; ++i) {
      *(u16x8*)&lds_a[arow][acol + i * 8] = ar[i];
      *(u16x8*)&lds_b[arow][acol + i * 8] = br[i];
    }
    if (kt < 15) {
      #pragma unroll
      for (int i = 0; i < 4; ++i) {
        ar[i] = *(const u16x8*)(aptr + (kt + 1) * 64 + i * 8);
        br[i] = *(const u16x8*)(bptr + (kt + 1) * 64 + i * 8);
      }
    }
    __syncthreads();
    #pragma unroll
    for (int kk = 0; kk < 2; ++kk) {
      const int kof = kk * 32 + g * 8;
      u16x8 afr[4], bfr[4];
      #pragma unroll
      for (int m = 0; m < 4; ++m) afr[m] = *(const u16x8*)&lds_a[wr * 64 + m * 16 + li][kof];
      #pragma unroll
      for (int n = 0; n < 4; ++n) bfr[n] = *(const u16x8*)&lds_b[wc * 64 + n * 16 + li][kof];
      #pragma unroll
      for (int m = 0; m < 4; ++m)
        #pragma unroll
        for (int n = 0; n < 4; ++n) acc[m][n] = mfma16(afr[m], bfr[n], acc[m][n]);
    }
    __syncthreads();
  }

  #pragma unroll
  for (int n = 0; n < 4; ++n) {
    const int col = nb * 128 + wc * 64 + n * 16 + li;
    const float bv = bias[col];
    const int h = col >> 6, hd = col & 63;
    #pragma unroll
    for (int m = 0; m < 4; ++m) {
      const int tok0 = mb * 128 + wr * 64 + m * 16 + g * 4;
      const int src = tok0 >> 12;          // 0..2 : q/k/v
      const int bb = (tok0 >> 11) & 1, s0 = tok0 & 2047;
      if (src < 2) {
        u16* dst = (src == 0) ? qp : kp;
        #pragma unroll
        for (int r = 0; r < 4; ++r)
          dst[(((size_t)bb * 16 + h) * 2048 + s0 + r) * 64 + hd] = f2bf(acc[m][n][r] + bv);
      } else {
        u16x4 p;
        #pragma unroll
        for (int r = 0; r < 4; ++r) p[r] = f2bf(acc[m][n][r] + bv);
        *(u16x4*)&vpt[(((size_t)bb * 16 + h) * 64 + hd) * 2048 + s0] = p;
      }
    }
  }
}

// ---------------- fused attention ----------------
// grid (32 qtile, 16 h, 2 b), 256 thr = 4 waves; wave owns 16 q-rows.
__global__ __launch_bounds__(256) void attn_kernel(
    const u16* __restrict__ qp, const u16* __restrict__ kp,
    const u16* __restrict__ vpt, const u64* __restrict__ mbits,
    float* __restrict__ attnw, u16* __restrict__ ctx) {
  __shared__ __attribute__((aligned(16))) u16 q_lds[64][72];
  __shared__ __attribute__((aligned(16))) u16 k_lds[64][72];
  __shared__ __attribute__((aligned(16))) u16 v_lds[64][72];
  __shared__ __attribute__((aligned(16))) u16 w_lds[64][72];
  __shared__ u64 m_lds[64][32];

  const int tid = threadIdx.x;
  const int lane = tid & 63, wv = tid >> 6;
  const int g = lane >> 4, li = lane & 15;
  const int qt = blockIdx.x, h = blockIdx.y, b = blockIdx.z;
  const int bh = b * 16 + h;
  const int q0 = qt * 64;
  const float scale = 0.125f;
  const int srow = tid >> 2;
  const int scol = (tid & 3) * 16;

  const u16* kbase = kp + ((size_t)bh * 2048 + srow) * 64 + scol;
  u16x8 k0 = *(const u16x8*)kbase;
  u16x8 k1 = *(const u16x8*)(kbase + 8);

  {
    const u16* qsrc = qp + ((size_t)bh * 2048 + q0 + srow) * 64 + scol;
    *(u16x8*)&q_lds[srow][scol] = *(const u16x8*)qsrc;
    *(u16x8*)&q_lds[srow][scol + 8] = *(const u16x8*)(qsrc + 8);
    const int mw0 = (tid & 3) * 8;
    #pragma unroll
    for (int i = 0; i < 8; ++i)
      m_lds[srow][mw0 + i] = mbits[((size_t)b * 2048 + q0 + srow) * 32 + mw0 + i];
  }

  float mlane[4], llane[4];
  #pragma unroll
  for (int r = 0; r < 4; ++r) { mlane[r] = -1e30f; llane[r] = 0.f; }

  __syncthreads();

  // ---- pass 1: stats (per-lane online, no per-iter shuffles) ----
  for (int kt = 0; kt < 32; ++kt) {
    *(u16x8*)&k_lds[srow][scol] = k0;
    *(u16x8*)&k_lds[srow][scol + 8] = k1;
    if (kt < 31) {
      k0 = *(const u16x8*)(kbase + (size_t)(kt + 1) * 4096);
      k1 = *(const u16x8*)(kbase + (size_t)(kt + 1) * 4096 + 8);
    }
    __syncthreads();
    f32x4 sc[4];
    #pragma unroll
    for (int n = 0; n < 4; ++n) sc[n] = f32x4{0.f, 0.f, 0.f, 0.f};
    #pragma unroll
    for (int kk = 0; kk < 2; ++kk) {
      const int kof = kk * 32 + g * 8;
      u16x8 aq = *(const u16x8*)&q_lds[wv * 16 + li][kof];
      #pragma unroll
      for (int n = 0; n < 4; ++n)
        sc[n] = mfma16(aq, *(const u16x8*)&k_lds[n * 16 + li][kof], sc[n]);
    }
    #pragma unroll
    for (int r = 0; r < 4; ++r) {
      const u64 mw = m_lds[wv * 16 + g * 4 + r][kt];
      float sv[4];
      #pragma unroll
      for (int n = 0; n < 4; ++n)
        sv[n] = ((mw >> (n * 16 + li)) & 1ull) ? sc[n][r] * scale : -1e9f;
      float pm = fmaxf(fmaxf(sv[0], sv[1]), fmaxf(sv[2], sv[3]));
      float mn = fmaxf(mlane[r], pm);
      float ps = __expf(sv[0] - mn) + __expf(sv[1] - mn) +
                 __expf(sv[2] - mn) + __expf(sv[3] - mn);
      llane[r] = llane[r] * __expf(mlane[r] - mn) + ps;
      mlane[r] = mn;
    }
    __syncthreads();
  }

  // ---- merge per-lane stats across the 16-lane row group ----
  float mrow[4], inv[4];
  #pragma unroll
  for (int r = 0; r < 4; ++r) {
    float m = mlane[r], l = llane[r];
    #pragma unroll
    for (int off = 1; off < 16; off <<= 1) {
      float mo = __shfl_xor(m, off, 16);
      float lo = __shfl_xor(l, off, 16);
      float mn = fmaxf(m, mo);
      l = l * __expf(m - mn) + lo * __expf(mo - mn);
      m = mn;
    }
    mrow[r] = m;
    inv[r] = 1.f / l;
  }

  const u16* vbase = vpt + ((size_t)bh * 64 + srow) * 2048 + scol;
  k0 = *(const u16x8*)kbase;
  k1 = *(const u16x8*)(kbase + 8);
  u16x8 v0 = *(const u16x8*)vbase;
  u16x8 v1 = *(const u16x8*)(vbase + 8);

  f32x4 cacc[4];
  #pragma unroll
  for (int n = 0; n < 4; ++n) cacc[n] = f32x4{0.f, 0.f, 0.f, 0.f};

  // ---- pass 2: weights out + PV ----
  for (int kt = 0; kt < 32; ++kt) {
    *(u16x8*)&k_lds[srow][scol] = k0;
    *(u16x8*)&k_lds[srow][scol + 8] = k1;
    *(u16x8*)&v_lds[srow][scol] = v0;
    *(u16x8*)&v_lds[srow][scol + 8] = v1;
    if (kt < 31) {
      k0 = *(const u16x8*)(kbase + (size_t)(kt + 1) * 4096);
      k1 = *(const u16x8*)(kbase + (size_t)(kt + 1) * 4096 + 8);
      v0 = *(const u16x8*)(vbase + (size_t)(kt + 1) * 64);
      v1 = *(const u16x8*)(vbase + (size_t)(kt + 1) * 64 + 8);
    }
    __syncthreads();
    f32x4 sc[4];
    #pragma unroll
    for (int n = 0; n < 4; ++n) sc[n] = f32x4{0.f, 0.f, 0.f, 0.f};
    #pragma unroll
    for (int kk = 0; kk < 2; ++kk) {
      const int kof = kk * 32 + g * 8;
      u16x8 aq = *(const u16x8*)&q_lds[wv * 16 + li][kof];
      #pragma unroll
      for (int n = 0; n < 4; ++n)
        sc[n] = mfma16(aq, *(const u16x8*)&k_lds[n * 16 + li][kof], sc[n]);
    }
    #pragma unroll
    for (int r = 0; r < 4; ++r) {
      const int row_l = wv * 16 + g * 4 + r;
      const u64 mw = m_lds[row_l][kt];
      float* wdst = attnw + ((size_t)bh * 2048 + q0 + row_l) * 2048 + kt * 64;
      #pragma unroll
      for (int n = 0; n < 4; ++n) {
        float sv = ((mw >> (n * 16 + li)) & 1ull) ? sc[n][r] * scale : -1e9f;
        float wn = __expf(sv - mrow[r]) * inv[r];
        __builtin_nontemporal_store(wn, wdst + n * 16 + li);
        w_lds[row_l][n * 16 + li] = f2bf(wn);
      }
    }
    #pragma unroll
    for (int kk = 0; kk < 2; ++kk) {
      const int kof = kk * 32 + g * 8;
      u16x8 aw = *(const u16x8*)&w_lds[wv * 16 + li][kof];
      #pragma unroll
      for (int n = 0; n < 4; ++n)
        cacc[n] = mfma16(aw, *(const u16x8*)&v_lds[n * 16 + li][kof], cacc[n]);
    }
    __syncthreads();
  }

  #pragma unroll
  for (int n = 0; n < 4; ++n)
    #pragma unroll
    for (int r = 0; r < 4; ++r) {
      const int row_l = wv * 16 + g * 4 + r;
      ctx[((size_t)b * 2048 + q0 + row_l) * 1024 + h * 64 + n * 16 + li] = f2bf(cacc[n][r]);
    }
}

// ---------------- output GEMM: out = ctx @ Wout^T + bout ----------------
__global__ __launch_bounds__(256) void out_kernel(
    const u16* __restrict__ ctxp, const u16* __restrict__ wb,
    const float* __restrict__ bias, float* __restrict__ out) {
  __shared__ __attribute__((aligned(16))) u16 lds_a[128][72];
  __shared__ __attribute__((aligned(16))) u16 lds_b[128][72];
  const int tid = threadIdx.x;
  const int lane = tid & 63, wv = tid >> 6;
  const int wr = wv >> 1, wc = wv & 1;
  const int g = lane >> 4, li = lane & 15;
  const int nb = blockIdx.x, mb = blockIdx.y;
  const int arow = tid >> 1;
  const int acol = (tid & 1) * 32;

  f32x4 acc[4][4];
  #pragma unroll
  for (int m = 0; m < 4; ++m)
    #pragma unroll
    for (int n = 0; n < 4; ++n) acc[m][n] = f32x4{0.f, 0.f, 0.f, 0.f};

  const u16* aptr = ctxp + (size_t)(mb * 128 + arow) * 1024 + acol;
  const u16* bptr = wb + (size_t)(nb * 128 + arow) * 1024 + acol;

  u16x8 ar[4], br[4];
  #pragma unroll
  for (int i = 0; i < 4; ++i) {
    ar[i] = *(const u16x8*)(aptr + i * 8);
    br[i] = *(const u16x8*)(bptr + i * 8);
  }

  for (int kt = 0; kt < 16; ++kt) {
    #pragma unroll
    for (int i = 0; i < 4; ++i) {
      *(u16x8*)&lds_a[arow][acol + i * 8] = ar[i];
      *(u16x8*)&lds_b[arow][acol + i * 8] = br[i];
    }
    if (kt < 15) {
      #pragma unroll
      for (int i = 0; i < 4; ++i) {
        ar[i] = *(const u16x8*)(aptr + (kt + 1) * 64 + i * 8);
        br[i] = *(const u16x8*)(bptr + (kt + 1) * 64 + i * 8);
      }
    }
    __syncthreads();
    #pragma unroll
    for (int kk = 0; kk < 2; ++kk) {
      const int kof = kk * 32 + g * 8;
      u16x8 afr[4], bfr[4];
      #pragma unroll
      for (int m = 0; m < 4; ++m) afr[m] = *(const u16x8*)&lds_a[wr * 64 + m * 16 + li][kof];
      #pragma unroll
      for (int n = 0; n < 4; ++n) bfr[n] = *(const u16x8*)&lds_b[wc * 64 + n * 16 + li][kof];
      #pragma unroll
      for (int m = 0; m < 4; ++m)
        #pragma unroll
        for (int n = 0; n < 4; ++n) acc[m][n] = mfma16(afr[m], bfr[n], acc[m][n]);
    }
    __syncthreads();
  }

  #pragma unroll
  for (int n = 0; n < 4; ++n) {
    const int col = nb * 128 + wc * 64 + n * 16 + li;
    const float bv = bias[col];
    #pragma unroll
    for (int m = 0; m < 4; ++m) {
      const int row0 = mb * 128 + wr * 64 + m * 16 + g * 4;
      #pragma unroll
      for (int r = 0; r < 4; ++r)
        __builtin_nontemporal_store(acc[m][n][r] + bv, out + (size_t)(row0 + r) * 1024 + col);
    }
  }
}

extern "C" void kernel_launch(void* const* d_in, const int* in_sizes, int n_in,
                              void* d_out, int out_size, void* d_ws, size_t ws_size,
                              hipStream_t stream) {
  const float* q    = (const float*)d_in[0];
  const float* k    = (const float*)d_in[1];
  const float* v    = (const float*)d_in[2];
  const int*   mask = (const int*)d_in[3];
  const float* Wq   = (const float*)d_in[4];
  const float* bq   = (const float*)d_in[5];
  const float* Wout = (const float*)d_in[6];
  const float* bout = (const float*)d_in[7];
  float* out   = (float*)d_out;
  float* attnw = out + (size_t)2 * 2048 * 1024;

  u16* ws16    = (u16*)d_ws;
  u16* wq_bf   = ws16;
  u16* wout_bf = ws16 + 1048576;
  u16* xb      = ws16 + 2097152;          // 12288 x 1024 bf16
  u16* qp      = ws16 + 14680064;
  u16* kp      = ws16 + 18874368;
  u16* vpt     = ws16 + 23068672;
  u16* ctx     = ws16 + 27262976;
  u64* mbits   = (u64*)(ws16 + 31457280);

  conv_kernel<<<1024, 256, 0, stream>>>(Wq, wq_bf, 262144);
  conv_kernel<<<1024, 256, 0, stream>>>(Wout, wout_bf, 262144);
  convqkv_kernel<<<6144, 256, 0, stream>>>(q, k, v, xb);
  maskpack_kernel<<<32768, 256, 0, stream>>>(mask, mbits);
  proj_kernel<<<dim3(8, 96), 256, 0, stream>>>(xb, wq_bf, bq, qp, kp, vpt);
  attn_kernel<<<dim3(32, 16, 2), 256, 0, stream>>>(qp, kp, vpt, mbits, attnw, ctx);
  out_kernel<<<dim3(8, 32), 256, 0, stream>>>(ctx, wout_bf, bout, out);
}